// Round 6
// baseline (89.208 us; speedup 1.0000x reference)
//
#include <hip/hip_runtime.h>

// Problem constants (match reference setup_inputs).
constexpr int Bc = 4;
constexpr int Nc = 2048;
constexpr int Dc = 3;
constexpr int Sc = 8;

typedef float f32x4 __attribute__((ext_vector_type(4)));

// y[b,s,i,j] = exp(-(sum_d |x[b,i,d]-x[b,j,d]|)^2 / (2*sigma_s^2))
// One block -> one (plane, i) row-segment, where plane = b*S + s = blockIdx.z.
// Each thread: 4 consecutive j, ONE sigma, one wave-contiguous store.
// blockIdx.z slowest -> concurrent blocks write within 1-2 consecutive 16MB
// planes: dense chip-wide write front (fill-like). R4 proved this is worth
// 1.54x vs 8 interleaved 16MB-strided streams (DRAM row thrash).
// R5 A/B: plain stores (not NT) — fill hits 6.7 TB/s through L2 write-back.
__global__ __launch_bounds__(256) void gauss_l1_kernel(
    const float* __restrict__ x,       // [B, N, D=3]
    const float* __restrict__ sigmas,  // [S=8]
    float* __restrict__ out)           // [B, S, N, N]
{
    const int plane = blockIdx.z;          // 0..31 == b*Sc + s
    const int b = plane >> 3;              // Sc == 8
    const int s = plane & 7;
    const int i = blockIdx.y;
    const int j0 = (blockIdx.x * blockDim.x + threadIdx.x) * 4;

    // x[b,i,:] — uniform across the block (scalar loads).
    const float* xi = x + ((size_t)b * Nc + i) * Dc;
    const float xi0 = xi[0], xi1 = xi[1], xi2 = xi[2];

    // x[b,j0..j0+3,:] — 12 consecutive floats -> 3 f32x4 loads (L2-resident).
    const f32x4* xj4 = reinterpret_cast<const f32x4*>(x + ((size_t)b * Nc + j0) * Dc);
    const f32x4 p0 = xj4[0];  // j0:{x,y,z}, j1:{x}
    const f32x4 p1 = xj4[1];  // j1:{y,z},   j2:{x,y}
    const f32x4 p2 = xj4[2];  // j2:{z},     j3:{x,y,z}

    float d2[4];
    {
        float d;
        d = fabsf(xi0 - p0.x) + fabsf(xi1 - p0.y) + fabsf(xi2 - p0.z); d2[0] = d * d;
        d = fabsf(xi0 - p0.w) + fabsf(xi1 - p1.x) + fabsf(xi2 - p1.y); d2[1] = d * d;
        d = fabsf(xi0 - p1.z) + fabsf(xi1 - p1.w) + fabsf(xi2 - p2.x); d2[2] = d * d;
        d = fabsf(xi0 - p2.y) + fabsf(xi1 - p2.z) + fabsf(xi2 - p2.w); d2[3] = d * d;
    }

    // -1/(2*sigma^2) for this block's single sigma (uniform scalar).
    const float sg = sigmas[s];
    const float inv = -1.0f / (2.0f * sg * sg);

    f32x4 v;
    v.x = __expf(d2[0] * inv);
    v.y = __expf(d2[1] * inv);
    v.z = __expf(d2[2] * inv);
    v.w = __expf(d2[3] * inv);

    const size_t off = ((size_t)plane * Nc + i) * Nc + j0;
    *reinterpret_cast<f32x4*>(out + off) = v;
}

extern "C" void kernel_launch(void* const* d_in, const int* in_sizes, int n_in,
                              void* d_out, int out_size, void* d_ws, size_t ws_size,
                              hipStream_t stream) {
    const float* x = (const float*)d_in[0];        // [B, N, 3] fp32
    const float* sigmas = (const float*)d_in[1];   // [8] fp32
    float* out = (float*)d_out;                    // [B, S, N, N] fp32

    dim3 block(256, 1, 1);
    dim3 grid(Nc / (256 * 4), Nc, Bc * Sc);        // (2, 2048, 32)
    gauss_l1_kernel<<<grid, block, 0, stream>>>(x, sigmas, out);
}

// Round 7
// 85.597 us; speedup vs baseline: 1.0422x; 1.0422x over previous
//
#include <hip/hip_runtime.h>

// Problem constants (match reference setup_inputs).
constexpr int Bc = 4;
constexpr int Nc = 2048;
constexpr int Dc = 3;
constexpr int Sc = 8;

typedef float f32x4 __attribute__((ext_vector_type(4)));

// y[b,s,i,j] = exp(-(sum_d |x[b,i,d]-x[b,j,d]|)^2 / (2*sigma_s^2))
// One block -> one (plane, i) row-segment, where plane = b*S + s = blockIdx.z.
// Each thread: 4 consecutive j, ONE sigma, one wave-contiguous NT store.
//
// Measured A/B ladder (MI355X, 537MB fp32 output):
//   R0  8-plane strided, plain stores:  130.9 us (4.1 TB/s)
//   R3  8-plane strided, NT stores:     131.8 us (NT neutral when strided)
//   R4  dense plane-major, NT stores:    85.3 us (6.30 TB/s)  <- this kernel
//   R5  dense plane-major, plain:        89.2 us (NT worth +4.6% when dense)
// Plane-major dispatch (blockIdx.z slowest) makes the chip-wide write front
// dense within 1-2 consecutive 16MB planes -> no DRAM row thrash (1.54x).
// NT bypasses L2 allocation; each store is a full 1KB wave burst already.
// Fill-kernel ceiling on same chip: 6.7 TB/s -> 94% achieved.
__global__ __launch_bounds__(256) void gauss_l1_kernel(
    const float* __restrict__ x,       // [B, N, D=3]
    const float* __restrict__ sigmas,  // [S=8]
    float* __restrict__ out)           // [B, S, N, N]
{
    const int plane = blockIdx.z;          // 0..31 == b*Sc + s
    const int b = plane >> 3;              // Sc == 8
    const int s = plane & 7;
    const int i = blockIdx.y;
    const int j0 = (blockIdx.x * blockDim.x + threadIdx.x) * 4;

    // x[b,i,:] — uniform across the block (scalar loads).
    const float* xi = x + ((size_t)b * Nc + i) * Dc;
    const float xi0 = xi[0], xi1 = xi[1], xi2 = xi[2];

    // x[b,j0..j0+3,:] — 12 consecutive floats -> 3 f32x4 loads (L2-resident).
    const f32x4* xj4 = reinterpret_cast<const f32x4*>(x + ((size_t)b * Nc + j0) * Dc);
    const f32x4 p0 = xj4[0];  // j0:{x,y,z}, j1:{x}
    const f32x4 p1 = xj4[1];  // j1:{y,z},   j2:{x,y}
    const f32x4 p2 = xj4[2];  // j2:{z},     j3:{x,y,z}

    float d2[4];
    {
        float d;
        d = fabsf(xi0 - p0.x) + fabsf(xi1 - p0.y) + fabsf(xi2 - p0.z); d2[0] = d * d;
        d = fabsf(xi0 - p0.w) + fabsf(xi1 - p1.x) + fabsf(xi2 - p1.y); d2[1] = d * d;
        d = fabsf(xi0 - p1.z) + fabsf(xi1 - p1.w) + fabsf(xi2 - p2.x); d2[2] = d * d;
        d = fabsf(xi0 - p2.y) + fabsf(xi1 - p2.z) + fabsf(xi2 - p2.w); d2[3] = d * d;
    }

    // -1/(2*sigma^2) for this block's single sigma (uniform scalar).
    const float sg = sigmas[s];
    const float inv = -1.0f / (2.0f * sg * sg);

    f32x4 v;
    v.x = __expf(d2[0] * inv);
    v.y = __expf(d2[1] * inv);
    v.z = __expf(d2[2] * inv);
    v.w = __expf(d2[3] * inv);

    const size_t off = ((size_t)plane * Nc + i) * Nc + j0;
    __builtin_nontemporal_store(v, reinterpret_cast<f32x4*>(out + off));
}

extern "C" void kernel_launch(void* const* d_in, const int* in_sizes, int n_in,
                              void* d_out, int out_size, void* d_ws, size_t ws_size,
                              hipStream_t stream) {
    const float* x = (const float*)d_in[0];        // [B, N, 3] fp32
    const float* sigmas = (const float*)d_in[1];   // [8] fp32
    float* out = (float*)d_out;                    // [B, S, N, N] fp32

    dim3 block(256, 1, 1);
    dim3 grid(Nc / (256 * 4), Nc, Bc * Sc);        // (2, 2048, 32)
    gauss_l1_kernel<<<grid, block, 0, stream>>>(x, sigmas, out);
}